// Round 4
// baseline (17.339 us; speedup 1.0000x reference)
//
#include <hip/hip_runtime.h>

#define BB 8
#define NN 4096
#define KK 2048
#define C4 64   // C/4 float4 per row

typedef float f32x4 __attribute__((ext_vector_type(4)));

// 512 blocks x 1024 threads (16 waves). Each block owns 64 consecutive output
// rows of one batch. Phase 1: all threads cooperatively sum idx[b, 0:rowStart)
// (<= 1008 int4 -> at most one int4 per thread) while wave 0 scans the block's
// own 64 idx values. Phase 2: each wave copies/zeros 4 rows (64 lanes x f32x4).
__global__ __launch_bounds__(1024) void topk_fused_kernel(const f32x4* __restrict__ x,
                                                          const int* __restrict__ idx,
                                                          f32x4* __restrict__ out) {
    const int bi = blockIdx.x;               // 0..511
    const int b = bi >> 6;                   // 64 blocks per batch
    const int rowStart = (bi & 63) << 6;     // 64 rows per block
    const int t = threadIdx.x;
    const int lane = t & 63;
    const int wave = t >> 6;                 // 0..15

    const int* idxB = idx + (size_t)b * NN;
    const int4* idxB4 = (const int4*)idxB;

    __shared__ int waveSum[16];
    __shared__ int pref[64];
    __shared__ int idxs[64];

    // ---- partial sum of idx[0:rowStart): at most one int4 per thread ----
    int partial = 0;
    const int n4 = rowStart >> 2;            // <= 1008
    if (t < n4) {
        int4 v = idxB4[t];
        partial = v.x + v.y + v.z + v.w;
    }
#pragma unroll
    for (int off = 32; off > 0; off >>= 1)
        partial += __shfl_down(partial, off, 64);
    if (lane == 0) waveSum[wave] = partial;

    // ---- wave 0: exclusive scan of this block's 64 idx values (independent of base) ----
    if (wave == 0) {
        const int myv = idxB[rowStart + lane];
        idxs[lane] = myv;
        int incl = myv;
#pragma unroll
        for (int off = 1; off < 64; off <<= 1) {
            int up = __shfl_up(incl, off, 64);
            if (lane >= off) incl += up;
        }
        pref[lane] = incl - myv;
    }
    __syncthreads();

    int base = 0;
#pragma unroll
    for (int w = 0; w < 16; ++w) base += waveSum[w];

    // ---- each wave copies/zeros 4 rows; nontemporal (streams touched once) ----
    const long long outRow0 = (long long)b * NN + rowStart;
    const long long xBase = (long long)b * KK + base;
#pragma unroll
    for (int r = 0; r < 4; ++r) {
        const int rib = wave * 4 + r;
        f32x4 val = (f32x4)(0.f);
        if (idxs[rib] > 0)
            val = __builtin_nontemporal_load(&x[(xBase + pref[rib]) * C4 + lane]);
        __builtin_nontemporal_store(val, &out[(outRow0 + rib) * C4 + lane]);
    }
}

extern "C" void kernel_launch(void* const* d_in, const int* in_sizes, int n_in,
                              void* d_out, int out_size, void* d_ws, size_t ws_size,
                              hipStream_t stream) {
    const float* x  = (const float*)d_in[0];   // (B, K, C) float32
    const int* idx  = (const int*)d_in[1];     // (B, N) int32
    // d_in[2] = A (B, N, N) -- only its shape matters; never read.
    float* out = (float*)d_out;                // (B, N, C) float32

    topk_fused_kernel<<<(BB * NN) / 64, 1024, 0, stream>>>(
        (const f32x4*)x, idx, (f32x4*)out);
}

// Round 5
// 14.821 us; speedup vs baseline: 1.1699x; 1.1699x over previous
//
#include <hip/hip_runtime.h>

#define BB 8
#define NN 4096
#define KK 2048
#define C4 64   // C/4 float4 per row

// 512 blocks x 1024 threads (16 waves). Each block owns 64 consecutive output
// rows of one batch. Phase 1: all threads cooperatively sum idx[b, 0:rowStart)
// (<= 1008 int4 -> at most one int4 per thread) while wave 0 scans the block's
// own 64 idx values. Phase 2: each wave copies/zeros 4 rows (64 lanes x float4).
// Plain (cached) loads/stores: the 48 MB working set is L3-resident across
// timed replays; nontemporal hints forfeited that (R4 regression).
__global__ __launch_bounds__(1024) void topk_fused_kernel(const float4* __restrict__ x,
                                                          const int* __restrict__ idx,
                                                          float4* __restrict__ out) {
    const int bi = blockIdx.x;               // 0..511
    const int b = bi >> 6;                   // 64 blocks per batch
    const int rowStart = (bi & 63) << 6;     // 64 rows per block
    const int t = threadIdx.x;
    const int lane = t & 63;
    const int wave = t >> 6;                 // 0..15

    const int* idxB = idx + (size_t)b * NN;
    const int4* idxB4 = (const int4*)idxB;

    __shared__ int waveSum[16];
    __shared__ int pref[64];
    __shared__ int idxs[64];

    // ---- partial sum of idx[0:rowStart): at most one int4 per thread ----
    int partial = 0;
    const int n4 = rowStart >> 2;            // <= 1008
    if (t < n4) {
        int4 v = idxB4[t];
        partial = v.x + v.y + v.z + v.w;
    }
#pragma unroll
    for (int off = 32; off > 0; off >>= 1)
        partial += __shfl_down(partial, off, 64);
    if (lane == 0) waveSum[wave] = partial;

    // ---- wave 0: exclusive scan of this block's 64 idx values ----
    if (wave == 0) {
        const int myv = idxB[rowStart + lane];
        idxs[lane] = myv;
        int incl = myv;
#pragma unroll
        for (int off = 1; off < 64; off <<= 1) {
            int up = __shfl_up(incl, off, 64);
            if (lane >= off) incl += up;
        }
        pref[lane] = incl - myv;
    }
    __syncthreads();

    int base = 0;
#pragma unroll
    for (int w = 0; w < 16; ++w) base += waveSum[w];

    // ---- each wave copies/zeros 4 rows ----
    const long long outRow0 = (long long)b * NN + rowStart;
    const long long xBase = (long long)b * KK + base;
#pragma unroll
    for (int r = 0; r < 4; ++r) {
        const int rib = wave * 4 + r;
        float4 val = make_float4(0.f, 0.f, 0.f, 0.f);
        if (idxs[rib] > 0)
            val = x[(xBase + pref[rib]) * C4 + lane];
        out[(outRow0 + rib) * C4 + lane] = val;
    }
}

extern "C" void kernel_launch(void* const* d_in, const int* in_sizes, int n_in,
                              void* d_out, int out_size, void* d_ws, size_t ws_size,
                              hipStream_t stream) {
    const float* x  = (const float*)d_in[0];   // (B, K, C) float32
    const int* idx  = (const int*)d_in[1];     // (B, N) int32
    // d_in[2] = A (B, N, N) -- only its shape matters; never read.
    float* out = (float*)d_out;                // (B, N, C) float32

    topk_fused_kernel<<<(BB * NN) / 64, 1024, 0, stream>>>(
        (const float4*)x, idx, (float4*)out);
}

// Round 6
// 13.749 us; speedup vs baseline: 1.2611x; 1.0779x over previous
//
#include <hip/hip_runtime.h>

#define BB 8
#define NN 4096
#define KK 2048
#define C4 64   // C/4 float4 per row

// 512 blocks x 1024 threads (16 waves); each block owns 64 consecutive output
// rows of one batch; each wave owns 4 rows.
// Phase 0 (no deps): each wave reads its own 4 idx values (one broadcast int4)
//   and immediately stores zeros for its unselected rows -- overlaps the
//   prologue latency with ~half the write stream.
// Phase 1: cooperative reduce of idx[b, 0:rowStart) (<=1 int4/thread) for the
//   global base; per-wave 4-sums into LDS for the within-block prefix.
// Phase 2: copy selected rows from x.
__global__ __launch_bounds__(1024) void topk_fused_kernel(const float4* __restrict__ x,
                                                          const int* __restrict__ idx,
                                                          float4* __restrict__ out) {
    const int bi = blockIdx.x;               // 0..511
    const int b = bi >> 6;                   // 64 blocks per batch
    const int rowStart = (bi & 63) << 6;     // 64 rows per block
    const int t = threadIdx.x;
    const int lane = t & 63;
    const int wave = t >> 6;                 // 0..15

    const int* idxB = idx + (size_t)b * NN;
    const int4* idxB4 = (const int4*)idxB;

    // ---- phase 0: this wave's 4 idx values; store zeros now (no deps) ----
    const int4 v4 = idxB4[(rowStart >> 2) + wave];     // wave-uniform broadcast
    const long long outRow0 = (long long)b * NN + rowStart + wave * 4;
    const float4 z = make_float4(0.f, 0.f, 0.f, 0.f);
    if (v4.x <= 0) out[(outRow0 + 0) * C4 + lane] = z;
    if (v4.y <= 0) out[(outRow0 + 1) * C4 + lane] = z;
    if (v4.z <= 0) out[(outRow0 + 2) * C4 + lane] = z;
    if (v4.w <= 0) out[(outRow0 + 3) * C4 + lane] = z;

    // ---- phase 1: base reduce (idx[0:rowStart)) + per-wave 4-sums ----
    __shared__ int waveSum[16];   // partial sums of idx[0:rowStart)
    __shared__ int waveLoc[16];   // each wave's sum of its own 4 idx values

    int partial = 0;
    const int n4 = rowStart >> 2;            // <= 1008 < 1024
    if (t < n4) {
        int4 v = idxB4[t];
        partial = v.x + v.y + v.z + v.w;
    }
#pragma unroll
    for (int off = 32; off > 0; off >>= 1)
        partial += __shfl_down(partial, off, 64);
    if (lane == 0) {
        waveSum[wave] = partial;
        waveLoc[wave] = v4.x + v4.y + v4.z + v4.w;
    }
    __syncthreads();

    int base = 0;
#pragma unroll
    for (int i = 0; i < 4; ++i) {
        const int4 s = ((const int4*)waveSum)[i];
        base += s.x + s.y + s.z + s.w;
    }
    int preW = 0;
    for (int w = 0; w < wave; ++w) preW += waveLoc[w];

    // ---- phase 2: copy selected rows ----
    const long long xRow = (long long)b * KK + base + preW;  // rank of 1st selected row here
    long long r = xRow;
    if (v4.x > 0) { out[(outRow0 + 0) * C4 + lane] = x[r * C4 + lane]; r += 1; }
    if (v4.y > 0) { out[(outRow0 + 1) * C4 + lane] = x[r * C4 + lane]; r += 1; }
    if (v4.z > 0) { out[(outRow0 + 2) * C4 + lane] = x[r * C4 + lane]; r += 1; }
    if (v4.w > 0) { out[(outRow0 + 3) * C4 + lane] = x[r * C4 + lane]; }
}

extern "C" void kernel_launch(void* const* d_in, const int* in_sizes, int n_in,
                              void* d_out, int out_size, void* d_ws, size_t ws_size,
                              hipStream_t stream) {
    const float* x  = (const float*)d_in[0];   // (B, K, C) float32
    const int* idx  = (const int*)d_in[1];     // (B, N) int32
    // d_in[2] = A (B, N, N) -- only its shape matters; never read.
    float* out = (float*)d_out;                // (B, N, C) float32

    topk_fused_kernel<<<(BB * NN) / 64, 1024, 0, stream>>>(
        (const float4*)x, idx, (float4*)out);
}